// Round 2
// baseline (2178.215 us; speedup 1.0000x reference)
//
#include <hip/hip_runtime.h>

#define NI0 288
#define NI1 512
#define NI2 256
#define NTOT 37748736

// ---- d_out float offsets (return-order concatenation)
#define O_XREC  0
#define O_ANEW  37748736
#define O_SCALE 75497472
#define O_GM0   75497473
#define O_GM1   75515905
#define O_GM2   75548673
#define O_GTR0  75565057
#define O_GTR1  75583489
#define O_GTR2  75616257
#define O_RM0   75632641
#define O_RM1   75715585
#define O_RM2   75977729

// ---- scratch layout:
//   big S/M buffer (9437184 floats) -> d_out + O_ANEW   (A_new written LAST)
//   small buffers -> head of d_out + O_XREC             (X_rec written by k_final after they are dead)
#define W_NC   0
#define W_Z    32768
#define W_Q    65536
#define W_Y    98304
#define W_U    131072
#define W_GT   163840
#define W_PN   196608
#define W_PZ   200704
#define W_CTC  204800
#define W_BINV 208896

// ============ Gram: P += Gm^T Gm (tile of 32 rows per block) ============
__global__ void __launch_bounds__(256) k_gram(const float* __restrict__ Gm, float* __restrict__ P) {
    __shared__ float t[32][64];
    const int tid = threadIdx.x;
    const int r0 = blockIdx.x * 32;
    #pragma unroll
    for (int i = 0; i < 8; ++i) {
        int idx = tid + i * 256;
        t[idx >> 6][idx & 63] = Gm[(r0 + (idx >> 6)) * 64 + (idx & 63)];
    }
    __syncthreads();
    const int p = tid & 63, qg = tid >> 6;
    float acc[16];
    #pragma unroll
    for (int q = 0; q < 16; ++q) acc[q] = 0.f;
    for (int rr = 0; rr < 32; ++rr) {
        float vp = t[rr][p];
        #pragma unroll
        for (int q = 0; q < 16; ++q) acc[q] += vp * t[rr][qg * 16 + q];
    }
    #pragma unroll
    for (int q = 0; q < 16; ++q) atomicAdd(&P[p * 64 + qg * 16 + q], acc[q]);
}

// ============ CtC[(c1a1),(c2a2)] = sum_{b1,b2} Pn[a1b1,a2b2]*Pz[b1c1,b2c2] ============
__global__ void __launch_bounds__(256) k_combine(const float* __restrict__ Pn, const float* __restrict__ Pz,
                                                 float* __restrict__ CtC) {
    int o = blockIdx.x * 256 + threadIdx.x;   // 4096 outputs
    int k1 = o >> 6, k2 = o & 63;
    int c1 = k1 >> 3, a1 = k1 & 7, c2 = k2 >> 3, a2 = k2 & 7;
    float acc = 0.f;
    #pragma unroll
    for (int b1 = 0; b1 < 8; ++b1)
        #pragma unroll
        for (int b2 = 0; b2 < 8; ++b2)
            acc += Pn[(a1 * 8 + b1) * 64 + a2 * 8 + b2] * Pz[(b1 * 8 + c1) * 64 + b2 * 8 + c2];
    CtC[o] = acc;
}

// ============ Binv = inv(CtC + c*I), Gauss-Jordan, PD so no pivoting ============
__global__ void __launch_bounds__(256) k_binv(const float* __restrict__ CtC, const float* __restrict__ alpha,
                                              const float* __restrict__ ni, const float* __restrict__ mu,
                                              int mode, float* __restrict__ Binv) {
    __shared__ float M[64][129];
    const int tid = threadIdx.x;
    const float cd = alpha[mode] + 0.5f * (mu[mode] + ni[mode]);
    for (int idx = tid; idx < 64 * 128; idx += 256) {
        int r = idx >> 7, c = idx & 127;
        float v;
        if (c < 64) v = CtC[r * 64 + c] + (c == r ? cd : 0.f);
        else        v = ((c - 64) == r) ? 1.f : 0.f;
        M[r][c] = v;
    }
    const int r = tid >> 2, c0 = (tid & 3) * 32;
    for (int p = 0; p < 64; ++p) {
        __syncthreads();
        float rp = 1.0f / M[p][p];
        __syncthreads();
        if (r == p) { for (int c = c0; c < c0 + 32; ++c) M[p][c] *= rp; }
        __syncthreads();
        float f = M[r][p];
        __syncthreads();
        if (r != p) { for (int c = c0; c < c0 + 32; ++c) M[r][c] -= f * M[p][c]; }
    }
    __syncthreads();
    for (int idx = tid; idx < 64 * 64; idx += 256)
        Binv[idx] = M[idx >> 6][64 + (idx & 63)];
}

// ============ stage1 mode0: S[(x,y),k] = sum_z (Xrec-A)[x,y,z] * Gmz[z,k] ============
__global__ void __launch_bounds__(256) k_s1_m0(const float* __restrict__ Xrec, const float* __restrict__ Aten,
                                               const float* __restrict__ Gmz, float* __restrict__ S) {
    __shared__ float Nt[128][65];
    __shared__ float Bt[64][64];
    const int tid = threadIdx.x;
    const int r0 = blockIdx.x * 128;           // row = x*512+y, 1152 blocks
    const int rg = tid & 31, kg = tid >> 5;    // kg 0..7
    float acc[4][8];
    #pragma unroll
    for (int i = 0; i < 4; ++i)
        #pragma unroll
        for (int j = 0; j < 8; ++j) acc[i][j] = 0.f;
    for (int zt = 0; zt < 4; ++zt) {
        __syncthreads();
        #pragma unroll
        for (int i = 0; i < 32; ++i) {
            int idx = tid + i * 256;
            int rr = idx >> 6, z = idx & 63;
            int g = (r0 + rr) * 256 + zt * 64 + z;
            Nt[rr][z] = Xrec[g] - Aten[g];
        }
        #pragma unroll
        for (int i = 0; i < 16; ++i) {
            int idx = tid + i * 256;
            Bt[idx >> 6][idx & 63] = Gmz[(zt * 64 + (idx >> 6)) * 64 + (idx & 63)];
        }
        __syncthreads();
        for (int z = 0; z < 64; ++z) {
            float b[8];
            #pragma unroll
            for (int kk = 0; kk < 8; ++kk) b[kk] = Bt[z][kg * 8 + kk];
            #pragma unroll
            for (int rr = 0; rr < 4; ++rr) {
                float n = Nt[rg + 32 * rr][z];
                #pragma unroll
                for (int kk = 0; kk < 8; ++kk) acc[rr][kk] += n * b[kk];
            }
        }
    }
    #pragma unroll
    for (int rr = 0; rr < 4; ++rr) {
        int row = r0 + rg + 32 * rr;
        #pragma unroll
        for (int kk = 0; kk < 8; ++kk) S[row * 64 + kg * 8 + kk] = acc[rr][kk];
    }
}

// ============ stage1 mode1: S[(y,z),k] = sum_x N[x,y,z] * Gmz[x,k] ============
__global__ void __launch_bounds__(256) k_s1_m1(const float* __restrict__ Xrec, const float* __restrict__ Aten,
                                               const float* __restrict__ Gmz, float* __restrict__ S) {
    __shared__ float Nt[8][256];
    __shared__ float Gt[8][64];
    const int tid = threadIdx.x;
    const int c0 = blockIdx.x * 256;           // S row chunk = (y*256+z), 512 blocks
    const int rg = tid & 31, kg = tid >> 5;
    float acc[8][8];
    #pragma unroll
    for (int i = 0; i < 8; ++i)
        #pragma unroll
        for (int j = 0; j < 8; ++j) acc[i][j] = 0.f;
    for (int xt = 0; xt < 36; ++xt) {
        __syncthreads();
        #pragma unroll
        for (int i = 0; i < 8; ++i) {
            int idx = tid + i * 256;
            int xx = idx >> 8, cc = idx & 255;
            int g = (xt * 8 + xx) * 131072 + c0 + cc;
            Nt[xx][cc] = Xrec[g] - Aten[g];
        }
        #pragma unroll
        for (int i = 0; i < 2; ++i) {
            int idx = tid + i * 256;
            Gt[idx >> 6][idx & 63] = Gmz[(xt * 8 + (idx >> 6)) * 64 + (idx & 63)];
        }
        __syncthreads();
        #pragma unroll
        for (int xx = 0; xx < 8; ++xx) {
            float b[8];
            #pragma unroll
            for (int kk = 0; kk < 8; ++kk) b[kk] = Gt[xx][kg * 8 + kk];
            #pragma unroll
            for (int rr = 0; rr < 8; ++rr) {
                float n = Nt[xx][rg + 32 * rr];
                #pragma unroll
                for (int kk = 0; kk < 8; ++kk) acc[rr][kk] += n * b[kk];
            }
        }
    }
    #pragma unroll
    for (int rr = 0; rr < 8; ++rr) {
        int row = c0 + rg + 32 * rr;
        #pragma unroll
        for (int kk = 0; kk < 8; ++kk) S[row * 64 + kg * 8 + kk] = acc[rr][kk];
    }
}

// ============ stage1 mode2: S[(x,z),k] = sum_y N[x,y,z] * Gmz[y,k] ============
__global__ void __launch_bounds__(256) k_s1_m2(const float* __restrict__ Xrec, const float* __restrict__ Aten,
                                               const float* __restrict__ Gmz, float* __restrict__ S) {
    __shared__ float Nt[8][128];
    __shared__ float Gt[8][64];
    const int tid = threadIdx.x;
    const int x = blockIdx.x >> 1, z0 = (blockIdx.x & 1) * 128;   // 576 blocks
    const int zg = tid & 31, kg = tid >> 5;
    float acc[4][8];
    #pragma unroll
    for (int i = 0; i < 4; ++i)
        #pragma unroll
        for (int j = 0; j < 8; ++j) acc[i][j] = 0.f;
    for (int yt = 0; yt < 64; ++yt) {
        __syncthreads();
        #pragma unroll
        for (int i = 0; i < 4; ++i) {
            int idx = tid + i * 256;
            int yy = idx >> 7, zz = idx & 127;
            int g = x * 131072 + (yt * 8 + yy) * 256 + z0 + zz;
            Nt[yy][zz] = Xrec[g] - Aten[g];
        }
        #pragma unroll
        for (int i = 0; i < 2; ++i) {
            int idx = tid + i * 256;
            Gt[idx >> 6][idx & 63] = Gmz[(yt * 8 + (idx >> 6)) * 64 + (idx & 63)];
        }
        __syncthreads();
        #pragma unroll
        for (int yy = 0; yy < 8; ++yy) {
            float b[8];
            #pragma unroll
            for (int kk = 0; kk < 8; ++kk) b[kk] = Gt[yy][kg * 8 + kk];
            #pragma unroll
            for (int zz = 0; zz < 4; ++zz) {
                float n = Nt[yy][zg + 32 * zz];
                #pragma unroll
                for (int kk = 0; kk < 8; ++kk) acc[zz][kk] += n * b[kk];
            }
        }
    }
    #pragma unroll
    for (int zz = 0; zz < 4; ++zz) {
        int row = x * 256 + z0 + zg + 32 * zz;
        #pragma unroll
        for (int kk = 0; kk < 8; ++kk) S[row * 64 + kg * 8 + kk] = acc[zz][kk];
    }
}

// ============ stage2: NC[blk, c*8+a] = sum_{l,b} Gn[l, a*8+b] * S[blk*rowA + l*rowB, b*8+c] ============
__global__ void __launch_bounds__(256) k_s2(const float* __restrict__ S, const float* __restrict__ Gn,
                                            float* __restrict__ NC, int L, int rowA, int rowB) {
    __shared__ float Sr[4][64];
    __shared__ float Gr[4][64];
    __shared__ float part[4][64];
    const int tid = threadIdx.x;
    const int blk = blockIdx.x;
    const int k = tid & 63, lg = tid >> 6;
    const int c = k >> 3, a = k & 7;
    float acc = 0.f;
    for (int l0 = 0; l0 < L; l0 += 4) {
        __syncthreads();
        {
            int lrow = tid >> 6, col = tid & 63;
            int l = l0 + lrow;
            int srow = blk * rowA + l * rowB;
            Sr[lrow][col] = S[srow * 64 + col];
            Gr[lrow][col] = Gn[l * 64 + col];
        }
        __syncthreads();
        #pragma unroll
        for (int b = 0; b < 8; ++b)
            acc += Gr[lg][a * 8 + b] * Sr[lg][b * 8 + c];
    }
    part[lg][k] = acc;
    __syncthreads();
    if (tid < 64) NC[blk * 64 + tid] = part[0][tid] + part[1][tid] + part[2][tid] + part[3][tid];
}

// ============ G_new = A_mat @ Binv, A_mat built in-flight; in-place into G ============
__global__ void __launch_bounds__(256) k_gupd(float* __restrict__ G, const float* __restrict__ NC,
                                              const float* __restrict__ Z, const float* __restrict__ Y,
                                              const float* __restrict__ Q, const float* __restrict__ U,
                                              const float* __restrict__ Binv,
                                              const float* __restrict__ alpha, const float* __restrict__ ni,
                                              const float* __restrict__ mu, int mode) {
    __shared__ float Bl[64][64];
    __shared__ float Al[4][64];
    const int tid = threadIdx.x;
    const int r4 = tid >> 6, k = tid & 63;
    const int row = blockIdx.x * 4 + r4;
    #pragma unroll
    for (int i = 0; i < 16; ++i) {
        int idx = tid + i * 256;
        Bl[idx >> 6][idx & 63] = Binv[idx];
    }
    const float al = alpha[mode], niv = ni[mode], muv = mu[mode];
    const int e = row * 64 + k;
    Al[r4][k] = NC[e] + 0.5f * muv * Z[e] - 0.5f * Y[e] + 0.5f * niv * Q[e] - 0.5f * U[e] + al * G[e];
    __syncthreads();
    float acc = 0.f;
    #pragma unroll 8
    for (int m = 0; m < 64; ++m) acc += Al[r4][m] * Bl[m][k];
    G[e] = acc;
}

// ============ R = W*R + Bp (elementwise, unaligned-safe scalar) ============
__global__ void __launch_bounds__(256) k_rupd(float* __restrict__ R, const float* __restrict__ W,
                                              const float* __restrict__ Bp, int n) {
    int i = blockIdx.x * 256 + threadIdx.x;
    if (i < n) R[i] = W[i] * R[i] + Bp[i];
}

// ============ Gt = ni*G + U ============
__global__ void __launch_bounds__(256) k_gt(const float* __restrict__ G, const float* __restrict__ U,
                                            float* __restrict__ Gt, const float* __restrict__ ni, int mode, int n) {
    int i = blockIdx.x * 256 + threadIdx.x;
    if (i < n) Gt[i] = ni[mode] * G[i] + U[i];
}

// ============ Q = Aq @ Gt   (In x In)@(In x 64) ============
__global__ void __launch_bounds__(256) k_qgemm(const float* __restrict__ Aq, const float* __restrict__ Gt,
                                               float* __restrict__ Q, int In) {
    __shared__ float Aql[4][512];
    __shared__ float Gl[64][64];
    const int tid = threadIdx.x;
    const int r4 = tid >> 6, k = tid & 63;
    const int row0 = blockIdx.x * 4;
    for (int idx = tid; idx < 4 * In; idx += 256) {
        int rr = idx / In, m = idx % In;
        Aql[rr][m] = Aq[(row0 + rr) * In + m];
    }
    float acc = 0.f;
    for (int m0 = 0; m0 < In; m0 += 64) {
        __syncthreads();
        #pragma unroll
        for (int i = 0; i < 16; ++i) {
            int idx = tid + i * 256;
            int mm = idx >> 6, kk = idx & 63;
            Gl[mm][kk] = (m0 + mm < In) ? Gt[(m0 + mm) * 64 + kk] : 0.f;
        }
        __syncthreads();
        int mend = (In - m0 < 64) ? (In - m0) : 64;
        for (int m = 0; m < mend; ++m) acc += Aql[r4][m0 + m] * Gl[m][k];
    }
    Q[(row0 + r4) * 64 + k] = acc;
}

// ============ Z = relu(G + Y/mu); U += ni*(G - Q); Y += mu*(G - Z) ============
__global__ void __launch_bounds__(256) k_zuy(const float* __restrict__ G, const float* __restrict__ Q,
                                             float* __restrict__ Z, float* __restrict__ U, float* __restrict__ Y,
                                             const float* __restrict__ ni, const float* __restrict__ mu,
                                             int mode, int n) {
    int i = blockIdx.x * 256 + threadIdx.x;
    if (i < n) {
        float muv = mu[mode], niv = ni[mode];
        float g = G[i], y = Y[i];
        float z = fmaxf(g + y / muv, 0.f);
        U[i] += niv * (g - Q[i]);
        Y[i] = y + muv * (g - z);
        Z[i] = z;
    }
}

// ============ Gtr[a, x, b] = Gm[x, a*8+b] ============
__global__ void __launch_bounds__(256) k_gtr(const float* __restrict__ Gm, float* __restrict__ Gtr, int In) {
    int i = blockIdx.x * 256 + threadIdx.x;   // < In*64, layout a*(In*8)+x*8+b
    int b = i & 7, x = (i >> 3) % In, a = i / (In * 8);
    Gtr[i] = Gm[x * 64 + a * 8 + b];
}

// ============ A_new + scale_new ============
__global__ void __launch_bounds__(256) k_anew(const float* __restrict__ Xrec, const float* __restrict__ Gcat,
                                              const float* __restrict__ Om, const float* __restrict__ scale,
                                              float* __restrict__ Anew, float* __restrict__ scale_out) {
    int i = blockIdx.x * 256 + threadIdx.x;   // < NTOT/4
    float sc = scale[0];
    if (blockIdx.x == 0 && threadIdx.x == 0) scale_out[0] = sc * 0.9f;
    float4 xr = ((const float4*)Xrec)[i];
    float4 gc = ((const float4*)Gcat)[i];
    float4 om = ((const float4*)Om)[i];
    float4 r;
    r.x = (xr.x - gc.x) * om.x; r.y = (xr.y - gc.y) * om.y;
    r.z = (xr.z - gc.z) * om.z; r.w = (xr.w - gc.w) * om.w;
    float4 o;
    o.x = (fabsf(r.x) > sc) ? r.x : 0.f;
    o.y = (fabsf(r.y) > sc) ? r.y : 0.f;
    o.z = (fabsf(r.z) > sc) ? r.z : 0.f;
    o.w = (fabsf(r.w) > sc) ? r.w : 0.f;
    ((float4*)Anew)[i] = o;
}

// ============ M[(x,y), a*8+c] = sum_b Gm0[x,a*8+b]*Gm1[y,b*8+c] ============
__global__ void __launch_bounds__(256) k_mbuild(const float* __restrict__ Gm0, const float* __restrict__ Gm1,
                                                float* __restrict__ M) {
    __shared__ float g0[64];
    const int tid = threadIdx.x;
    const int x = blockIdx.x >> 1, yh = blockIdx.x & 1;   // 576 blocks
    if (tid < 64) g0[tid] = Gm0[x * 64 + tid];
    __syncthreads();
    const int y = yh * 256 + tid;
    float g1[64];
    #pragma unroll
    for (int j = 0; j < 64; ++j) g1[j] = Gm1[y * 64 + j];
    float* Mo = M + (x * 512 + y) * 64;
    #pragma unroll
    for (int a = 0; a < 8; ++a) {
        #pragma unroll
        for (int c = 0; c < 8; ++c) {
            float s = 0.f;
            #pragma unroll
            for (int b = 0; b < 8; ++b) s += g0[a * 8 + b] * g1[b * 8 + c];
            Mo[a * 8 + c] = s;
        }
    }
}

// ============ X_rec_new[(xy), z] = (sum_k M[xy,k]*Gm2[z, swz(k)])*(1-Om) + X*Om*Om ============
__global__ void __launch_bounds__(256) k_final(const float* __restrict__ M, const float* __restrict__ Gm2,
                                               const float* __restrict__ Om, const float* __restrict__ X,
                                               float* __restrict__ out) {
    __shared__ float Ml[64][65];
    __shared__ float G2[128][65];
    const int tid = threadIdx.x;
    const int rb = blockIdx.x >> 1, z0 = (blockIdx.x & 1) * 128;   // 4608 blocks
    const int r0 = rb * 64;
    #pragma unroll
    for (int i = 0; i < 16; ++i) {
        int idx = tid + i * 256;
        Ml[idx >> 6][idx & 63] = M[(r0 + (idx >> 6)) * 64 + (idx & 63)];
    }
    #pragma unroll
    for (int i = 0; i < 32; ++i) {
        int idx = tid + i * 256;
        G2[idx >> 6][idx & 63] = Gm2[(z0 + (idx >> 6)) * 64 + (idx & 63)];
    }
    __syncthreads();
    const int zg = tid & 31, rgq = tid >> 5;   // rgq 0..7
    float acc[8][4];
    #pragma unroll
    for (int i = 0; i < 8; ++i)
        #pragma unroll
        for (int j = 0; j < 4; ++j) acc[i][j] = 0.f;
    for (int k = 0; k < 64; ++k) {
        int a = k >> 3, cc = k & 7;
        int g2k = cc * 8 + a;
        float m[8];
        #pragma unroll
        for (int rr = 0; rr < 8; ++rr) m[rr] = Ml[rgq + 8 * rr][k];
        #pragma unroll
        for (int zz = 0; zz < 4; ++zz) {
            float g = G2[zg + 32 * zz][g2k];
            #pragma unroll
            for (int rr = 0; rr < 8; ++rr) acc[rr][zz] += m[rr] * g;
        }
    }
    #pragma unroll
    for (int rr = 0; rr < 8; ++rr) {
        int row = r0 + rgq + 8 * rr;
        #pragma unroll
        for (int zz = 0; zz < 4; ++zz) {
            int gi = row * 256 + z0 + zg + 32 * zz;
            float om = Om[gi];
            out[gi] = acc[rr][zz] * (1.f - om) + X[gi] * om * om;
        }
    }
}

extern "C" void kernel_launch(void* const* d_in, const int* in_sizes, int n_in,
                              void* d_out, int out_size, void* d_ws, size_t ws_size,
                              hipStream_t stream) {
    const float* X     = (const float*)d_in[0];
    const float* Om    = (const float*)d_in[1];
    const float* Xrec  = (const float*)d_in[2];
    const float* Aten  = (const float*)d_in[3];
    const float* Gcat  = (const float*)d_in[4];
    const float* scale = (const float*)d_in[5];
    const float* Gm_in[3] = {(const float*)d_in[6], (const float*)d_in[7], (const float*)d_in[8]};
    const float* Rm_in[3] = {(const float*)d_in[12], (const float*)d_in[13], (const float*)d_in[14]};
    const float* Wm[3] = {(const float*)d_in[15], (const float*)d_in[16], (const float*)d_in[17]};
    const float* Bm[3] = {(const float*)d_in[18], (const float*)d_in[19], (const float*)d_in[20]};
    const float* alpha = (const float*)d_in[21];
    const float* ni    = (const float*)d_in[22];
    const float* mu    = (const float*)d_in[23];

    float* out = (float*)d_out;
    float* oGm[3]  = {out + O_GM0, out + O_GM1, out + O_GM2};
    float* oGtr[3] = {out + O_GTR0, out + O_GTR1, out + O_GTR2};
    float* oRm[3]  = {out + O_RM0, out + O_RM1, out + O_RM2};
    const int In[3]  = {NI0, NI1, NI2};
    const int RmN[3] = {NI0 * NI0, NI1 * NI1, NI2 * NI2};

    // scratch inside d_out (see layout note at top) — no d_ws dependency
    float* wS    = out + O_ANEW;       // 9437184 floats; A_new is written last
    float* wNC   = out + O_XREC + W_NC;
    float* wZ    = out + O_XREC + W_Z;
    float* wQ    = out + O_XREC + W_Q;
    float* wY    = out + O_XREC + W_Y;
    float* wU    = out + O_XREC + W_U;
    float* wGt   = out + O_XREC + W_GT;
    float* wPn   = out + O_XREC + W_PN;
    float* wPz   = out + O_XREC + W_PZ;
    float* wCtC  = out + O_XREC + W_CTC;
    float* wBinv = out + O_XREC + W_BINV;

    // init working G_m / R_m in the output buffer
    for (int i = 0; i < 3; ++i) {
        hipMemcpyAsync(oGm[i], Gm_in[i], (size_t)In[i] * 64 * sizeof(float), hipMemcpyDeviceToDevice, stream);
        hipMemcpyAsync(oRm[i], Rm_in[i], (size_t)RmN[i] * sizeof(float), hipMemcpyDeviceToDevice, stream);
    }

    for (int i = 0; i < 3; ++i) {
        const int nn = (i + 1) % 3, zz = (i + 2) % 3;
        // CtC = f(Gram(Gm[n]), Gram(Gm[z])); Binv = inv(CtC + c I)
        hipMemsetAsync(wPn, 0, 4096 * sizeof(float), stream);
        hipMemsetAsync(wPz, 0, 4096 * sizeof(float), stream);
        k_gram<<<In[nn] / 32, 256, 0, stream>>>(oGm[nn], wPn);
        k_gram<<<In[zz] / 32, 256, 0, stream>>>(oGm[zz], wPz);
        k_combine<<<16, 256, 0, stream>>>(wPn, wPz, wCtC);
        k_binv<<<1, 256, 0, stream>>>(wCtC, alpha, ni, mu, i, wBinv);
        // NC = N_(i) @ C  via two-stage factorization (no C materialization)
        if (i == 0)      k_s1_m0<<<1152, 256, 0, stream>>>(Xrec, Aten, oGm[2], wS);
        else if (i == 1) k_s1_m1<<<512, 256, 0, stream>>>(Xrec, Aten, oGm[0], wS);
        else             k_s1_m2<<<576, 256, 0, stream>>>(Xrec, Aten, oGm[1], wS);
        if (i == 0)      k_s2<<<NI0, 256, 0, stream>>>(wS, oGm[1], wNC, 512, 512, 1);
        else if (i == 1) k_s2<<<NI1, 256, 0, stream>>>(wS, oGm[2], wNC, 256, 256, 1);
        else             k_s2<<<NI2, 256, 0, stream>>>(wS, oGm[0], wNC, 288, 1, 256);
        // ADMM state init: Z=Q=G, U=Y=0
        const int nf = In[i] * 64;
        hipMemcpyAsync(wZ, oGm[i], (size_t)nf * sizeof(float), hipMemcpyDeviceToDevice, stream);
        hipMemcpyAsync(wQ, oGm[i], (size_t)nf * sizeof(float), hipMemcpyDeviceToDevice, stream);
        hipMemsetAsync(wU, 0, (size_t)nf * sizeof(float), stream);
        hipMemsetAsync(wY, 0, (size_t)nf * sizeof(float), stream);
        for (int t = 0; t < 3; ++t) {
            k_gupd<<<In[i] / 4, 256, 0, stream>>>(oGm[i], wNC, wZ, wY, wQ, wU, wBinv, alpha, ni, mu, i);
            k_rupd<<<(RmN[i] + 255) / 256, 256, 0, stream>>>(oRm[i], Wm[i], Bm[i], RmN[i]);
            k_gt<<<nf / 256, 256, 0, stream>>>(oGm[i], wU, wGt, ni, i, nf);
            k_qgemm<<<In[i] / 4, 256, 0, stream>>>(oRm[i], wGt, wQ, In[i]);
            k_zuy<<<nf / 256, 256, 0, stream>>>(oGm[i], wQ, wZ, wU, wY, ni, mu, i, nf);
        }
    }
    for (int i = 0; i < 3; ++i)
        k_gtr<<<In[i] * 64 / 256, 256, 0, stream>>>(oGm[i], oGtr[i], In[i]);

    // Order matters: k_final reads M from the A_new region; k_anew (A_new) runs LAST.
    k_mbuild<<<576, 256, 0, stream>>>(oGm[0], oGm[1], wS);
    k_final<<<4608, 256, 0, stream>>>(wS, oGm[2], Om, X, out + O_XREC);
    k_anew<<<NTOT / 1024, 256, 0, stream>>>(Xrec, Gcat, Om, scale, out + O_ANEW, out + O_SCALE);
}